// Round 4
// baseline (196.951 us; speedup 1.0000x reference)
//
#include <hip/hip_runtime.h>
#include <math.h>
#include <float.h>

#define W 1024
#define IMG_SZ (1024*1024)
#define N_IMG 32
#define RPS 16                          // interior rows per strip
#define VSTR 64                         // vertical strips per half: 63*16+14 = 1022
#define NSTRIP (N_IMG*2*VSTR)           // 4096 strips (half-row wide), one per wave
#define NBLK 1024                       // 1024 blocks * 4 waves = 4096 waves

// curv = Dxy*(Dx-Dy)^2 / (2h*(Dx^2+Dy^2)^1.5 + 16 h^4 * 1e-8)
#define TWO_H    0.122f
#define C_EPS    2.2153332e-12f         // 16 * 0.061^4 * 1e-8

// One half-row (512 px), per-lane view: 8 contiguous px (x = sx + 8*lane .. +7),
// plus one wave-uniform broadcast halo scalar (the cross-seam neighbor).
struct Row8 { float4 a, b; float hb; }; // 9 VGPR

__device__ __forceinline__ float bperm(int addr, float x) {
    return __int_as_float(__builtin_amdgcn_ds_bpermute(addr, __float_as_int(x)));
}

__device__ __forceinline__ void issue_row(const float* __restrict__ rv,
                                          const float* __restrict__ rh, Row8& v) {
    v.a  = *reinterpret_cast<const float4*>(rv);
    v.b  = *reinterpret_cast<const float4*>(rv + 4);
    v.hb = *rh;                         // uniform address -> 1-line broadcast load
}

// lane halos: l = lane-1's px7 (b.w), r = lane+1's px0 (a.x); seam lane uses hb.
// Non-seam edge lanes keep clamped garbage -- feeds only edge-killed pixels.
__device__ __forceinline__ void halo2(int addrL, int addrR, bool selL, bool selR,
                                      const Row8& v, float& hl, float& hr) {
    const float l = bperm(addrL, v.b.w);
    const float r = bperm(addrR, v.a.x);
    hl = selL ? v.hb : l;
    hr = selR ? v.hb : r;
}

__device__ __forceinline__ void unpack(const Row8& v, float hl, float hr, float w[10]) {
    w[0]=hl;
    w[1]=v.a.x; w[2]=v.a.y; w[3]=v.a.z; w[4]=v.a.w;
    w[5]=v.b.x; w[6]=v.b.y; w[7]=v.b.z; w[8]=v.b.w;
    w[9]=hr;
}

struct Px { float num, den, mn; };

__device__ __forceinline__ Px px(const float T[10], const float M[10], const float B[10],
                                 const float G[10], int j) {
    Px p;
    const float Dx  = M[j+2] - M[j];
    const float Dy  = G[j+1];           // B[j+1] - T[j+1]
    const float Dxy = G[j+2] - G[j];    // (B[j+2]-T[j+2]) - (B[j]-T[j])
    const float dif = Dx - Dy;
    p.num = Dxy * (dif * dif);
    const float s = Dx*Dx + Dy*Dy;
    p.den = TWO_H * (s * __builtin_amdgcn_sqrtf(s)) + C_EPS;
    const float c = M[j+1];
    p.mn = fminf(fminf(c*M[j], c*M[j+2]), fminf(c*T[j+1], c*B[j+1]));
    return p;
}

// shared reciprocal for two pixels: den>=C_EPS so den*den >= 4.9e-24 (no underflow)
__device__ __forceinline__ void pair(const Px& a, const Px& b, float ea, float eb,
                                     float& fsum, int& cnt) {
    const float rc = __builtin_amdgcn_rcpf(a.den * b.den);
    const float t0 = a.num * (b.den * rc);
    const float t1 = b.num * (a.den * rc);
    const float cr0 = fmaxf(t0*t0 - 1.0f, 0.0f);
    const float cr1 = fmaxf(t1*t1 - 1.0f, 0.0f);
    const bool k0 = fmaxf(a.mn, ea) < 0.0f;
    const bool k1 = fmaxf(b.mn, eb) < 0.0f;
    fsum += k0 ? cr0 : 0.0f;
    fsum += k1 ? cr1 : 0.0f;
    cnt += __popcll(__ballot(k0));      // scalar-pipe; cnt becomes wave-uniform
    cnt += __popcll(__ballot(k1));
}

__device__ __forceinline__ void do_row8(const float T[10], const float M[10], const float B[10],
                                        float e0, float e3, float& fsum, int& cnt) {
    float G[10];
#pragma unroll
    for (int j = 0; j < 10; ++j) G[j] = B[j] - T[j];
#pragma unroll
    for (int j = 0; j < 8; j += 2) {
        const Px p0 = px(T, M, B, G, j);
        const Px p1 = px(T, M, B, G, j + 1);
        pair(p0, p1, (j == 0) ? e0 : -FLT_MAX, (j == 6) ? e3 : -FLT_MAX, fsum, cnt);
    }
}

__global__ __launch_bounds__(256, 4) void curv_partial(const float* __restrict__ phi,
                                                       double* __restrict__ partial, int nb) {
    const int q = threadIdx.x;
    const int lane = q & 63;
    const int wv = q >> 6;
    const int addrL = ((lane == 0)  ? 0  : (lane - 1)) << 2;
    const int addrR = ((lane == 63) ? 63 : (lane + 1)) << 2;

    double sum = 0.0, dcnt = 0.0;
    const int nw = nb * 4;              // total waves

    // one strip (16 interior rows x 512 px of one image) per wave; waves independent
    for (int sidx = (int)blockIdx.x * 4 + wv; sidx < NSTRIP; sidx += nw) {
        const int n    = sidx >> 7;     // / 128
        const int rem  = sidx & 127;
        const int half = rem & 1;       // adjacent waves share rows -> L2 locality
        const int s    = rem >> 1;
        const int y0   = 1 + s * RPS;
        const int nr   = (RPS < 1022 - s * RPS) ? RPS : (1022 - s * RPS); // 16, tail 14
        const float* img = phi + (size_t)n * IMG_SZ;
        const float* bv  = img + half * 512 + lane * 8;
        const float* bh  = img + (half ? 511 : 512);    // seam neighbor (uniform)

        // seam/edge selection for this strip
        const bool selL = (lane == 0)  && (half == 1);  // left halo from broadcast
        const bool selR = (lane == 63) && (half == 0);  // right halo from broadcast
        const float e0 = ((lane == 0)  && (half == 0)) ? 1.0f : -FLT_MAX;  // kills x=0
        const float e3 = ((lane == 63) && (half == 1)) ? 1.0f : -FLT_MAX;  // kills x=1023

        Row8 V[4];                      // ring: row (y0-1+t) in V[t&3]
        float HL[4], HR[4];
        issue_row(bv + (size_t)(y0 - 1) * W, bh + (size_t)(y0 - 1) * W, V[0]);
        issue_row(bv + (size_t)(y0)     * W, bh + (size_t)(y0)     * W, V[1]);
        issue_row(bv + (size_t)(y0 + 1) * W, bh + (size_t)(y0 + 1) * W, V[2]);
        halo2(addrL, addrR, selL, selR, V[0], HL[0], HR[0]);
        halo2(addrL, addrR, selL, selR, V[1], HL[1], HR[1]);

        float fs = 0.0f;
        int ct = 0;
        for (int i4 = 0; i4 < RPS; i4 += 4) {       // ring period 4: indices static
#pragma unroll
            for (int k = 0; k < 4; ++k) {
                const int i = i4 + k;
                if (i < nr) {
                    if (i + 1 < nr)      // prefetch row y0+i+2 (B of step i+1), <=1023
                        issue_row(bv + (size_t)(y0 + i + 2) * W,
                                  bh + (size_t)(y0 + i + 2) * W, V[(k + 3) & 3]);
                    // finish halo of this step's B row (loaded one step earlier)
                    halo2(addrL, addrR, selL, selR, V[(k + 2) & 3],
                          HL[(k + 2) & 3], HR[(k + 2) & 3]);
                    float Tw[10], Mw[10], Bw[10];
                    unpack(V[k & 3],       HL[k & 3],       HR[k & 3],       Tw);
                    unpack(V[(k + 1) & 3], HL[(k + 1) & 3], HR[(k + 1) & 3], Mw);
                    unpack(V[(k + 2) & 3], HL[(k + 2) & 3], HR[(k + 2) & 3], Bw);
                    do_row8(Tw, Mw, Bw, e0, e3, fs, ct);
                }
            }
        }
        sum  += (double)fs;
        dcnt += (double)ct;             // wave-uniform
    }

    // per-lane fs -> wave sum; cnt already wave-uniform
    for (int off = 32; off > 0; off >>= 1)
        sum += __shfl_down(sum, off, 64);
    __shared__ double lsum[4], lcnt[4];
    if (lane == 0) { lsum[wv] = sum; lcnt[wv] = dcnt; }
    __syncthreads();
    if (q == 0) {
        partial[blockIdx.x]      = lsum[0] + lsum[1] + lsum[2] + lsum[3];
        partial[nb + blockIdx.x] = lcnt[0] + lcnt[1] + lcnt[2] + lcnt[3];
    }
}

__global__ __launch_bounds__(256) void curv_final(const double* __restrict__ partial,
                                                  int nb, float* __restrict__ out) {
    double s = 0.0, c = 0.0;
    for (int i = threadIdx.x; i < nb; i += 256) {
        s += partial[i];
        c += partial[nb + i];
    }
    for (int off = 32; off > 0; off >>= 1) {
        s += __shfl_down(s, off, 64);
        c += __shfl_down(c, off, 64);
    }
    __shared__ double lsum[4], lcnt[4];
    const int lane = threadIdx.x & 63, wv = threadIdx.x >> 6;
    if (lane == 0) { lsum[wv] = s; lcnt[wv] = c; }
    __syncthreads();
    if (threadIdx.x == 0) {
        const double S = lsum[0] + lsum[1] + lsum[2] + lsum[3];
        const double C = lcnt[0] + lcnt[1] + lcnt[2] + lcnt[3];
        out[0] = (float)(S / (C + 1e-8));
    }
}

extern "C" void kernel_launch(void* const* d_in, const int* in_sizes, int n_in,
                              void* d_out, int out_size, void* d_ws, size_t ws_size,
                              hipStream_t stream) {
    const float* phi = (const float*)d_in[0];
    float* out = (float*)d_out;
    double* partial = (double*)d_ws;

    int nb = NBLK;
    const size_t need = (size_t)nb * 2 * sizeof(double);
    if (ws_size < need) {
        nb = (int)(ws_size / (2 * sizeof(double)));
        if (nb < 1) nb = 1;
    }

    curv_partial<<<nb, 256, 0, stream>>>(phi, partial, nb);
    curv_final<<<1, 256, 0, stream>>>(partial, nb, out);
}